// Round 12
// baseline (194.996 us; speedup 1.0000x reference)
//
#include <hip/hip_runtime.h>

// GaussianDynamics recurrent cell as a parallel affine scan — persistent blocks.
// x_t = S_t x_{t-1} + o_t,  S_t = I + (A - xic_t C) dt,  o_t = xic_t dy_t
// out_t = C x_{t-1} dt  (pre-update state)
//
// R12 vs R11 (98us, additive mem+compute convoy): persistent 8-rows-per-block
// with ZERO-extra-LDS double buffering: each wave reads only its OWN LDS
// quarter, so after its ds_read+lgkmcnt(0) the quarter is dead -> re-stage the
// NEXT row's global_load_lds into the same bytes while computing this row.
// Next-row loads are therefore queued during compute => the per-CU memory
// pipe never starves at row boundaries. Grid 2048 = 256 CU x 8 blocks: one
// launch generation, no mid-kernel retires.
//  - vmcnt(2) [r=0] / vmcnt(4) [r>0]: drain this row's 4 gl_lds only; dy(2)
//    + prev stores(2) remain counted; compiler's reg-dep waits cover dy/x0.
//  - raw s_barrier + lgkmcnt(0) only (no vmcnt drain) for the wsum exchange;
//    wsum ping-pong by row parity (wave skew <= 1 region).
//  - sched_barrier(0) pins issue order around hand-written waits (rule #18).
//  - Full unroll (8 rows) keeps dy-next regs and x0 static-indexed (rule #20).

constexpr int BATCH = 16384;
constexpr int TLEN  = 1000;
constexpr int TPB   = 256;
constexpr int SPT   = 4;               // 1000/4 = 250 full chunks
constexpr int ROWS  = 8;               // rows per persistent block
constexpr int NBLK  = BATCH / ROWS;    // 2048 = 256 CUs x 8 blocks

typedef float vfloat4 __attribute__((ext_vector_type(4)));
typedef float vfloat2 __attribute__((ext_vector_type(2)));

template <int CTRL, int ROWMASK>
__device__ __forceinline__ float dppf(float oldv, float srcv) {
    return __int_as_float(__builtin_amdgcn_update_dpp(
        __float_as_int(oldv), __float_as_int(srcv), CTRL, ROWMASK, 0xf, false));
}

__global__ __launch_bounds__(TPB, 8) void gd_scan_kernel(
    const float* __restrict__ xicovs,  // [B,T,2,2]
    const float* __restrict__ dyv,     // [B,T,2]
    const float* __restrict__ cA,      // [2,2]
    const float* __restrict__ Cm,      // [2,2]
    const float* __restrict__ x0,      // [B,2]
    const float* __restrict__ dtp,     // [1]
    float* __restrict__ out)           // [B,T,2] then [B,2]
{
    __shared__ vfloat4 s_xc[1024];        // 16 KB, quarter per wave, reused per row
    __shared__ float wsum[2][TPB / 64][6];

    const int tid  = threadIdx.x;
    const int lane = tid & 63;
    const int wv   = tid >> 6;
    const int base = blockIdx.x * ROWS;

    const int t0  = tid * SPT;
    const int t0m = (t0 <= TLEN - SPT) ? t0 : (TLEN - SPT);
    const bool valid = (t0 < TLEN);

    // stage row RR's xicov into this wave's quarter (4x gl_lds, pre-swizzled src)
#define STAGE_GL(RR)                                                            \
    do {                                                                        \
        const float* rowx_ = xicovs + (size_t)(RR) * (TLEN * 4);                \
        _Pragma("unroll")                                                       \
        for (int k = 0; k < 4; ++k) {                                           \
            const int pw_ = k * 64 + lane;                                      \
            const int gw_ = pw_ ^ ((pw_ >> 3) & 7);                             \
            int g_ = 256 * wv + gw_;                                            \
            if (g_ > TLEN - 1) g_ = TLEN - 1;                                   \
            __builtin_amdgcn_global_load_lds(                                   \
                (const __attribute__((address_space(1))) void*)(rowx_ + (size_t)g_ * 4), \
                (__attribute__((address_space(3))) void*)&s_xc[wv * 256 + k * 64],       \
                16, 0, 0);                                                      \
        }                                                                       \
    } while (0)

    // ---- prologue: x0 for all 8 rows (uniform; scalar or vector - counts are
    //      agnostic: iter-0 vmcnt(2) drains anything older than dy) ----
    float x0s[2 * ROWS];
#pragma unroll
    for (int rr = 0; rr < ROWS; ++rr) {
        x0s[2 * rr]     = x0[2 * (base + rr)];
        x0s[2 * rr + 1] = x0[2 * (base + rr) + 1];
    }

    // uniform params
    const float dts = dtp[0];
    const vfloat2 CdColA = {Cm[0] * dts, Cm[2] * dts};
    const vfloat2 CdColB = {Cm[1] * dts, Cm[3] * dts};
    const vfloat2 nCdRow0 = {-Cm[0] * dts, -Cm[1] * dts};
    const vfloat2 nCdRow1 = {-Cm[2] * dts, -Cm[3] * dts};
    const vfloat2 AdRow0 = {1.f + cA[0] * dts, cA[1] * dts};
    const vfloat2 AdRow1 = {cA[2] * dts, 1.f + cA[3] * dts};

    // ---- prologue: stage row 0 (gl x4 then dy x2 - issue order matters) ----
    STAGE_GL(base);
    __builtin_amdgcn_sched_barrier(0);
    vfloat4 dyA = reinterpret_cast<const vfloat4*>(dyv + (size_t)base * (TLEN * 2))[t0m >> 1];
    vfloat4 dyB = reinterpret_cast<const vfloat4*>(dyv + (size_t)base * (TLEN * 2))[(t0m >> 1) + 1];
    __builtin_amdgcn_sched_barrier(0);

#pragma unroll
    for (int r = 0; r < ROWS; ++r) {
        const int row = base + r;

        // ---- drain THIS row's 4 gl_lds only (dy + prev stores stay in flight) ----
        if (r == 0) asm volatile("s_waitcnt vmcnt(2)" ::: "memory");
        else        asm volatile("s_waitcnt vmcnt(4)" ::: "memory");
        __builtin_amdgcn_sched_barrier(0);

        // ---- read own 4 timesteps (swizzled ds_read_b128); quarter then dead ----
        vfloat4 xc[SPT];
#pragma unroll
        for (int s = 0; s < SPT; ++s) {
            const int gw  = 4 * lane + s;
            const int pos = gw ^ ((gw >> 3) & 7);
            xc[s] = s_xc[wv * 256 + pos];
        }
        asm volatile("s_waitcnt lgkmcnt(0)" ::: "memory");
        __builtin_amdgcn_sched_barrier(0);

        // ---- re-stage NEXT row into the same quarter + dy into fresh regs ----
        vfloat4 dyAn = dyA, dyBn = dyB;
        if (r + 1 < ROWS) {
            STAGE_GL(row + 1);
            const vfloat4* gdn = reinterpret_cast<const vfloat4*>(
                dyv + (size_t)(row + 1) * (TLEN * 2));
            dyAn = gdn[t0m >> 1];
            dyBn = gdn[(t0m >> 1) + 1];
        }
        __builtin_amdgcn_sched_barrier(0);

        const float dy0s[SPT] = {dyA.x, dyA.z, dyB.x, dyB.z};
        const float dy1s[SPT] = {dyA.y, dyA.w, dyB.y, dyB.w};

        // ---- per-step affine rows + compose (packed f32) ----
        vfloat2 Sa[SPT], Sb[SPT], ov[SPT];
        vfloat2 mA = {1.f, 0.f}, mB = {0.f, 1.f}, cc = {0.f, 0.f};
#pragma unroll
        for (int s = 0; s < SPT; ++s) {
            const vfloat4 xi = xc[s];
            const vfloat2 sa = AdRow0 + xi.x * nCdRow0 + xi.y * nCdRow1;
            const vfloat2 sb = AdRow1 + xi.z * nCdRow0 + xi.w * nCdRow1;
            const float o0 = xi.x * dy0s[s] + xi.y * dy1s[s];
            const float o1 = xi.z * dy0s[s] + xi.w * dy1s[s];
            Sa[s] = sa; Sb[s] = sb; ov[s] = vfloat2{o0, o1};
            const vfloat2 nA = sa.x * mA + sa.y * mB;
            const vfloat2 nB = sb.x * mA + sb.y * mB;
            const float nc0 = sa.x * cc.x + sa.y * cc.y + o0;
            const float nc1 = sb.x * cc.x + sb.y * cc.y + o1;
            mA = nA; mB = nB; cc = vfloat2{nc0, nc1};
        }
        if (!valid) { mA = vfloat2{1.f, 0.f}; mB = vfloat2{0.f, 1.f}; cc = vfloat2{0.f, 0.f}; }

        // ---- wave-level inclusive scan via DPP ----
#define SCAN_STEP(CTRL, RM)                                          \
        do {                                                         \
            vfloat2 smA, smB, scc;                                   \
            smA.x = dppf<CTRL, RM>(1.f, mA.x);                       \
            smA.y = dppf<CTRL, RM>(0.f, mA.y);                       \
            smB.x = dppf<CTRL, RM>(0.f, mB.x);                       \
            smB.y = dppf<CTRL, RM>(1.f, mB.y);                       \
            scc.x = dppf<CTRL, RM>(0.f, cc.x);                       \
            scc.y = dppf<CTRL, RM>(0.f, cc.y);                       \
            const vfloat2 nA = mA.x * smA + mA.y * smB;              \
            const vfloat2 nB = mB.x * smA + mB.y * smB;              \
            const float nc0 = mA.x * scc.x + mA.y * scc.y + cc.x;    \
            const float nc1 = mB.x * scc.x + mB.y * scc.y + cc.y;    \
            mA = nA; mB = nB; cc = vfloat2{nc0, nc1};                \
        } while (0)

        SCAN_STEP(0x111, 0xf);
        SCAN_STEP(0x112, 0xf);
        SCAN_STEP(0x114, 0xf);
        SCAN_STEP(0x118, 0xf);
        SCAN_STEP(0x142, 0xa);
        SCAN_STEP(0x143, 0xc);
#undef SCAN_STEP

        // ---- inter-wave fixup: raw barrier, lgkm-only drain, parity wsum ----
        const int pr = r & 1;
        if (lane == 63) {
            wsum[pr][wv][0] = mA.x; wsum[pr][wv][1] = mA.y;
            wsum[pr][wv][2] = mB.x; wsum[pr][wv][3] = mB.y;
            wsum[pr][wv][4] = cc.x; wsum[pr][wv][5] = cc.y;
        }
        asm volatile("s_waitcnt lgkmcnt(0)" ::: "memory");
        __builtin_amdgcn_s_barrier();

        vfloat2 pA = {1.f, 0.f}, pB = {0.f, 1.f}, pc = {0.f, 0.f};
        for (int w = 0; w < wv; ++w) {
            const vfloat2 tA = {wsum[pr][w][0], wsum[pr][w][1]};
            const vfloat2 tB = {wsum[pr][w][2], wsum[pr][w][3]};
            const vfloat2 tc = {wsum[pr][w][4], wsum[pr][w][5]};
            const vfloat2 nA = tA.x * pA + tA.y * pB;
            const vfloat2 nB = tB.x * pA + tB.y * pB;
            const float nc0 = tA.x * pc.x + tA.y * pc.y + tc.x;
            const float nc1 = tB.x * pc.x + tB.y * pc.y + tc.y;
            pA = nA; pB = nB; pc = vfloat2{nc0, nc1};
        }

        // ---- within-wave exclusive = inclusive of lane-1 ----
        vfloat2 eA, eB, ec;
        eA.x = __shfl_up(mA.x, 1); eA.y = __shfl_up(mA.y, 1);
        eB.x = __shfl_up(mB.x, 1); eB.y = __shfl_up(mB.y, 1);
        ec.x = __shfl_up(cc.x, 1); ec.y = __shfl_up(cc.y, 1);
        if (lane == 0) { eA = vfloat2{1.f, 0.f}; eB = vfloat2{0.f, 1.f}; ec = vfloat2{0.f, 0.f}; }

        const vfloat2 EA = eA.x * pA + eA.y * pB;
        const vfloat2 EB = eB.x * pA + eB.y * pB;
        const float Ec0 = eA.x * pc.x + eA.y * pc.y + ec.x;
        const float Ec1 = eB.x * pc.x + eB.y * pc.y + ec.y;

        float xq0 = EA.x * x0s[2 * r] + EA.y * x0s[2 * r + 1] + Ec0;
        float xq1 = EB.x * x0s[2 * r] + EB.y * x0s[2 * r + 1] + Ec1;

        // ---- replay chunk, emit outputs ----
        vfloat2 op[SPT];
#pragma unroll
        for (int s = 0; s < SPT; ++s) {
            op[s] = xq0 * CdColA + xq1 * CdColB;
            const float nx0 = Sa[s].x * xq0 + Sa[s].y * xq1 + ov[s].x;
            const float nx1 = Sb[s].x * xq0 + Sb[s].y * xq1 + ov[s].y;
            xq0 = nx0; xq1 = nx1;
        }

        if (valid) {
            float* ob = out + (size_t)row * (TLEN * 2) + (size_t)t0 * 2;
            vfloat4 w0 = {op[0].x, op[0].y, op[1].x, op[1].y};
            vfloat4 w1 = {op[2].x, op[2].y, op[3].x, op[3].y};
            __builtin_nontemporal_store(w0, reinterpret_cast<vfloat4*>(ob));
            __builtin_nontemporal_store(w1, reinterpret_cast<vfloat4*>(ob) + 1);
        }
        if (t0 == TLEN - SPT) {
            vfloat2 xf = {xq0, xq1};
            __builtin_nontemporal_store(
                xf, reinterpret_cast<vfloat2*>(out + (size_t)BATCH * (TLEN * 2) + 2 * row));
        }

        dyA = dyAn; dyB = dyBn;
    }
#undef STAGE_GL
}

extern "C" void kernel_launch(void* const* d_in, const int* in_sizes, int n_in,
                              void* d_out, int out_size, void* d_ws, size_t ws_size,
                              hipStream_t stream) {
    const float* xicovs = (const float*)d_in[0];
    const float* dyv    = (const float*)d_in[1];
    const float* cA     = (const float*)d_in[2];
    const float* Cm     = (const float*)d_in[3];
    const float* x0     = (const float*)d_in[4];
    const float* dtp    = (const float*)d_in[5];
    float* out = (float*)d_out;

    gd_scan_kernel<<<NBLK, TPB, 0, stream>>>(xicovs, dyv, cA, Cm, x0, dtp, out);
}

// Round 13
// 149.968 us; speedup vs baseline: 1.3003x; 1.3003x over previous
//
#include <hip/hip_runtime.h>

// GaussianDynamics recurrent cell as a parallel affine scan — persistent blocks.
// x_t = S_t x_{t-1} + o_t,  S_t = I + (A - xic_t C) dt,  o_t = xic_t dy_t
// out_t = C x_{t-1} dt  (pre-update state)
//
// R13 = R12 (spilled: FETCH/WRITE +228MB symmetric = scratch) minus register
// pressure:
//  - NO dy prefetch regs: dy(r) issued at TOP of iter r (before the vmcnt
//    drain) -> latency hides under drain+ds_read+S-compose. Saves 8-16 VGPR.
//  - vmcnt ledger (iter top queue = [gl(r)x4, st(r-1)x2], +dy x2):
//    vmcnt(4) (r=0: vmcnt(2)) drains exactly gl(r); compiler's dy-use wait
//    (<=4) drains dy/stores, keeps gl(r+1) prefetch in flight.
//  - x0 loaded in prologue BEFORE STAGE_GL(0): oldest in queue -> covered by
//    any drain (safe for s_load or VMEM lowering); static-indexed post-unroll.
//  - Everything else = R12: 2048 blocks x 8 rows (one resident generation),
//    re-stage own DEAD LDS quarter (zero-extra-LDS dbuf), raw s_barrier with
//    lgkm-only drain, wsum parity ping-pong, DPP scan, packed f32 math.

constexpr int BATCH = 16384;
constexpr int TLEN  = 1000;
constexpr int TPB   = 256;
constexpr int SPT   = 4;               // 1000/4 = 250 full chunks
constexpr int ROWS  = 8;               // rows per persistent block
constexpr int NBLK  = BATCH / ROWS;    // 2048 = 256 CUs x 8 blocks

typedef float vfloat4 __attribute__((ext_vector_type(4)));
typedef float vfloat2 __attribute__((ext_vector_type(2)));

template <int CTRL, int ROWMASK>
__device__ __forceinline__ float dppf(float oldv, float srcv) {
    return __int_as_float(__builtin_amdgcn_update_dpp(
        __float_as_int(oldv), __float_as_int(srcv), CTRL, ROWMASK, 0xf, false));
}

__global__ __launch_bounds__(TPB, 8) void gd_scan_kernel(
    const float* __restrict__ xicovs,  // [B,T,2,2]
    const float* __restrict__ dyv,     // [B,T,2]
    const float* __restrict__ cA,      // [2,2]
    const float* __restrict__ Cm,      // [2,2]
    const float* __restrict__ x0,      // [B,2]
    const float* __restrict__ dtp,     // [1]
    float* __restrict__ out)           // [B,T,2] then [B,2]
{
    __shared__ vfloat4 s_xc[1024];        // 16 KB, quarter per wave, reused per row
    __shared__ float wsum[2][TPB / 64][6];

    const int tid  = threadIdx.x;
    const int lane = tid & 63;
    const int wv   = tid >> 6;
    const int base = blockIdx.x * ROWS;

    const int t0  = tid * SPT;
    const int t0m = (t0 <= TLEN - SPT) ? t0 : (TLEN - SPT);
    const bool valid = (t0 < TLEN);

#define STAGE_GL(RR)                                                            \
    do {                                                                        \
        const float* rowx_ = xicovs + (size_t)(RR) * (TLEN * 4);                \
        _Pragma("unroll")                                                       \
        for (int k = 0; k < 4; ++k) {                                           \
            const int pw_ = k * 64 + lane;                                      \
            const int gw_ = pw_ ^ ((pw_ >> 3) & 7);                             \
            int g_ = 256 * wv + gw_;                                            \
            if (g_ > TLEN - 1) g_ = TLEN - 1;                                   \
            __builtin_amdgcn_global_load_lds(                                   \
                (const __attribute__((address_space(1))) void*)(rowx_ + (size_t)g_ * 4), \
                (__attribute__((address_space(3))) void*)&s_xc[wv * 256 + k * 64],       \
                16, 0, 0);                                                      \
        }                                                                       \
    } while (0)

    // ---- prologue: x0 + params FIRST (oldest in vmem queue if VMEM-lowered;
    //      drained before any gl_lds by every subsequent wait) ----
    float x0s[2 * ROWS];
#pragma unroll
    for (int rr = 0; rr < ROWS; ++rr) {
        x0s[2 * rr]     = x0[2 * (base + rr)];
        x0s[2 * rr + 1] = x0[2 * (base + rr) + 1];
    }
    const float dts = dtp[0];
    const vfloat2 CdColA = {Cm[0] * dts, Cm[2] * dts};
    const vfloat2 CdColB = {Cm[1] * dts, Cm[3] * dts};
    const vfloat2 nCdRow0 = {-Cm[0] * dts, -Cm[1] * dts};
    const vfloat2 nCdRow1 = {-Cm[2] * dts, -Cm[3] * dts};
    const vfloat2 AdRow0 = {1.f + cA[0] * dts, cA[1] * dts};
    const vfloat2 AdRow1 = {cA[2] * dts, 1.f + cA[3] * dts};

    __builtin_amdgcn_sched_barrier(0);
    STAGE_GL(base);
    __builtin_amdgcn_sched_barrier(0);

#pragma unroll
    for (int r = 0; r < ROWS; ++r) {
        const int row = base + r;

        // ---- issue dy(r) now; latency hides under drain + ds_read + compose ----
        const vfloat4* gd4 = reinterpret_cast<const vfloat4*>(dyv + (size_t)row * (TLEN * 2));
        const vfloat4 dyA = gd4[t0m >> 1];
        const vfloat4 dyB = gd4[(t0m >> 1) + 1];
        __builtin_amdgcn_sched_barrier(0);

        // ---- drain exactly this row's 4 gl_lds ----
        if (r == 0) asm volatile("s_waitcnt vmcnt(2)" ::: "memory");
        else        asm volatile("s_waitcnt vmcnt(4)" ::: "memory");
        __builtin_amdgcn_sched_barrier(0);

        // ---- read own 4 timesteps (swizzled ds_read_b128); quarter then dead ----
        vfloat4 xc[SPT];
#pragma unroll
        for (int s = 0; s < SPT; ++s) {
            const int gw  = 4 * lane + s;
            const int pos = gw ^ ((gw >> 3) & 7);
            xc[s] = s_xc[wv * 256 + pos];
        }
        asm volatile("s_waitcnt lgkmcnt(0)" ::: "memory");
        __builtin_amdgcn_sched_barrier(0);

        // ---- re-stage NEXT row into the same (dead) quarter ----
        if (r + 1 < ROWS) STAGE_GL(row + 1);
        __builtin_amdgcn_sched_barrier(0);

        const float dy0s[SPT] = {dyA.x, dyA.z, dyB.x, dyB.z};
        const float dy1s[SPT] = {dyA.y, dyA.w, dyB.y, dyB.w};

        // ---- per-step affine rows + compose (packed f32) ----
        vfloat2 Sa[SPT], Sb[SPT], ov[SPT];
        vfloat2 mA = {1.f, 0.f}, mB = {0.f, 1.f}, cc = {0.f, 0.f};
#pragma unroll
        for (int s = 0; s < SPT; ++s) {
            const vfloat4 xi = xc[s];
            const vfloat2 sa = AdRow0 + xi.x * nCdRow0 + xi.y * nCdRow1;
            const vfloat2 sb = AdRow1 + xi.z * nCdRow0 + xi.w * nCdRow1;
            const float o0 = xi.x * dy0s[s] + xi.y * dy1s[s];
            const float o1 = xi.z * dy0s[s] + xi.w * dy1s[s];
            Sa[s] = sa; Sb[s] = sb; ov[s] = vfloat2{o0, o1};
            const vfloat2 nA = sa.x * mA + sa.y * mB;
            const vfloat2 nB = sb.x * mA + sb.y * mB;
            const float nc0 = sa.x * cc.x + sa.y * cc.y + o0;
            const float nc1 = sb.x * cc.x + sb.y * cc.y + o1;
            mA = nA; mB = nB; cc = vfloat2{nc0, nc1};
        }
        if (!valid) { mA = vfloat2{1.f, 0.f}; mB = vfloat2{0.f, 1.f}; cc = vfloat2{0.f, 0.f}; }

        // ---- wave-level inclusive scan via DPP ----
#define SCAN_STEP(CTRL, RM)                                          \
        do {                                                         \
            vfloat2 smA, smB, scc;                                   \
            smA.x = dppf<CTRL, RM>(1.f, mA.x);                       \
            smA.y = dppf<CTRL, RM>(0.f, mA.y);                       \
            smB.x = dppf<CTRL, RM>(0.f, mB.x);                       \
            smB.y = dppf<CTRL, RM>(1.f, mB.y);                       \
            scc.x = dppf<CTRL, RM>(0.f, cc.x);                       \
            scc.y = dppf<CTRL, RM>(0.f, cc.y);                       \
            const vfloat2 nA = mA.x * smA + mA.y * smB;              \
            const vfloat2 nB = mB.x * smA + mB.y * smB;              \
            const float nc0 = mA.x * scc.x + mA.y * scc.y + cc.x;    \
            const float nc1 = mB.x * scc.x + mB.y * scc.y + cc.y;    \
            mA = nA; mB = nB; cc = vfloat2{nc0, nc1};                \
        } while (0)

        SCAN_STEP(0x111, 0xf);
        SCAN_STEP(0x112, 0xf);
        SCAN_STEP(0x114, 0xf);
        SCAN_STEP(0x118, 0xf);
        SCAN_STEP(0x142, 0xa);
        SCAN_STEP(0x143, 0xc);
#undef SCAN_STEP

        // ---- inter-wave fixup: raw barrier, lgkm-only drain, parity wsum ----
        const int pr = r & 1;
        if (lane == 63) {
            wsum[pr][wv][0] = mA.x; wsum[pr][wv][1] = mA.y;
            wsum[pr][wv][2] = mB.x; wsum[pr][wv][3] = mB.y;
            wsum[pr][wv][4] = cc.x; wsum[pr][wv][5] = cc.y;
        }
        asm volatile("s_waitcnt lgkmcnt(0)" ::: "memory");
        __builtin_amdgcn_s_barrier();

        vfloat2 pA = {1.f, 0.f}, pB = {0.f, 1.f}, pc = {0.f, 0.f};
        for (int w = 0; w < wv; ++w) {
            const vfloat2 tA = {wsum[pr][w][0], wsum[pr][w][1]};
            const vfloat2 tB = {wsum[pr][w][2], wsum[pr][w][3]};
            const vfloat2 tc = {wsum[pr][w][4], wsum[pr][w][5]};
            const vfloat2 nA = tA.x * pA + tA.y * pB;
            const vfloat2 nB = tB.x * pA + tB.y * pB;
            const float nc0 = tA.x * pc.x + tA.y * pc.y + tc.x;
            const float nc1 = tB.x * pc.x + tB.y * pc.y + tc.y;
            pA = nA; pB = nB; pc = vfloat2{nc0, nc1};
        }

        // ---- within-wave exclusive = inclusive of lane-1 ----
        vfloat2 eA, eB, ec;
        eA.x = __shfl_up(mA.x, 1); eA.y = __shfl_up(mA.y, 1);
        eB.x = __shfl_up(mB.x, 1); eB.y = __shfl_up(mB.y, 1);
        ec.x = __shfl_up(cc.x, 1); ec.y = __shfl_up(cc.y, 1);
        if (lane == 0) { eA = vfloat2{1.f, 0.f}; eB = vfloat2{0.f, 1.f}; ec = vfloat2{0.f, 0.f}; }

        const vfloat2 EA = eA.x * pA + eA.y * pB;
        const vfloat2 EB = eB.x * pA + eB.y * pB;
        const float Ec0 = eA.x * pc.x + eA.y * pc.y + ec.x;
        const float Ec1 = eB.x * pc.x + eB.y * pc.y + ec.y;

        float xq0 = EA.x * x0s[2 * r] + EA.y * x0s[2 * r + 1] + Ec0;
        float xq1 = EB.x * x0s[2 * r] + EB.y * x0s[2 * r + 1] + Ec1;

        // ---- replay chunk, emit outputs ----
        vfloat2 op[SPT];
#pragma unroll
        for (int s = 0; s < SPT; ++s) {
            op[s] = xq0 * CdColA + xq1 * CdColB;
            const float nx0 = Sa[s].x * xq0 + Sa[s].y * xq1 + ov[s].x;
            const float nx1 = Sb[s].x * xq0 + Sb[s].y * xq1 + ov[s].y;
            xq0 = nx0; xq1 = nx1;
        }

        if (valid) {
            float* ob = out + (size_t)row * (TLEN * 2) + (size_t)t0 * 2;
            vfloat4 w0 = {op[0].x, op[0].y, op[1].x, op[1].y};
            vfloat4 w1 = {op[2].x, op[2].y, op[3].x, op[3].y};
            __builtin_nontemporal_store(w0, reinterpret_cast<vfloat4*>(ob));
            __builtin_nontemporal_store(w1, reinterpret_cast<vfloat4*>(ob) + 1);
        }
        if (t0 == TLEN - SPT) {
            vfloat2 xf = {xq0, xq1};
            __builtin_nontemporal_store(
                xf, reinterpret_cast<vfloat2*>(out + (size_t)BATCH * (TLEN * 2) + 2 * row));
        }
    }
#undef STAGE_GL
}

extern "C" void kernel_launch(void* const* d_in, const int* in_sizes, int n_in,
                              void* d_out, int out_size, void* d_ws, size_t ws_size,
                              hipStream_t stream) {
    const float* xicovs = (const float*)d_in[0];
    const float* dyv    = (const float*)d_in[1];
    const float* cA     = (const float*)d_in[2];
    const float* Cm     = (const float*)d_in[3];
    const float* x0     = (const float*)d_in[4];
    const float* dtp    = (const float*)d_in[5];
    float* out = (float*)d_out;

    gd_scan_kernel<<<NBLK, TPB, 0, stream>>>(xicovs, dyv, cA, Cm, x0, dtp, out);
}

// Round 14
// 97.497 us; speedup vs baseline: 2.0000x; 1.5382x over previous
//
#include <hip/hip_runtime.h>

// GaussianDynamics recurrent cell as a parallel affine scan.
// x_t = S_t x_{t-1} + o_t,  S_t = I + (A - xic_t C) dt,  o_t = xic_t dy_t
// out_t = C x_{t-1} dt  (pre-update state)
//
// R14 = R10 verbatim (97.7us, best). Final structure:
//  - 1 row/block, 16384 blocks, 256 threads, SPT=4 (250 full chunks).
//  - Per-wave self-staging via global_load_lds(16B) into own LDS quarter,
//    XOR-involution source pre-swizzle (G21); single intra-wave vmcnt drain.
//  - dy loaded direct per-thread (2x contiguous dwordx4).
//  - Packed-f32 (v_pk_fma) affine algebra; DPP wave scan (row_shr/row_bcast
//    with identity fill); one __syncthreads for the 4-wave fixup.
//  - Nontemporal vectorized stores.
// REJECTED by experiment: row pipelining / persistent blocks (R4/R8/R12/R13:
// occupancy loss, scratch spill, L3-retention loss all exceed overlap gain);
// SPT=8 (R9: 64B lane-stride stores inflate WRITE_SIZE 1.5x); split vmcnt
// (R11: neutral). Plateau ~98us = 85% of the 83us cold-traffic roofline.

constexpr int BATCH = 16384;
constexpr int TLEN  = 1000;
constexpr int TPB   = 256;
constexpr int SPT   = 4;     // TPB*SPT = 1024 >= TLEN; 1000/4=250 full chunks

typedef float vfloat4 __attribute__((ext_vector_type(4)));
typedef float vfloat2 __attribute__((ext_vector_type(2)));

template <int CTRL, int ROWMASK>
__device__ __forceinline__ float dppf(float oldv, float srcv) {
    return __int_as_float(__builtin_amdgcn_update_dpp(
        __float_as_int(oldv), __float_as_int(srcv), CTRL, ROWMASK, 0xf, false));
}

__global__ __launch_bounds__(TPB, 8) void gd_scan_kernel(
    const float* __restrict__ xicovs,  // [B,T,2,2]
    const float* __restrict__ dyv,     // [B,T,2]
    const float* __restrict__ cA,      // [2,2]
    const float* __restrict__ Cm,      // [2,2]
    const float* __restrict__ x0,      // [B,2]
    const float* __restrict__ dtp,     // [1]
    float* __restrict__ out)           // [B,T,2] then [B,2]
{
    __shared__ vfloat4 s_xc[1024];        // AoS granules (16B = one timestep)
    __shared__ float wsum[TPB / 64][6];

    const int b    = blockIdx.x;
    const int tid  = threadIdx.x;
    const int lane = tid & 63;
    const int wv   = tid >> 6;

    const int t0  = tid * SPT;
    const int t0m = (t0 <= TLEN - SPT) ? t0 : (TLEN - SPT);
    const bool valid = (t0 < TLEN);       // threads 250..255 idle (identity)

    const float* rowx = xicovs + (size_t)b * TLEN * 4;

    // ---- per-wave self-staging: 4x global_load_lds(16B) into own quarter,
    //      XOR-involution pre-swizzled source (G21) ----
#pragma unroll
    for (int k = 0; k < 4; ++k) {
        const int pw = k * 64 + lane;
        const int gw = pw ^ ((pw >> 3) & 7);
        int g = 256 * wv + gw;
        if (g > TLEN - 1) g = TLEN - 1;
        __builtin_amdgcn_global_load_lds(
            (const __attribute__((address_space(1))) void*)(rowx + (size_t)g * 4),
            (__attribute__((address_space(3))) void*)&s_xc[wv * 256 + k * 64],
            16, 0, 0);
    }

    // ---- dy: per-thread contiguous 32B (2x dwordx4), in flight with staging ----
    const vfloat4* gd4 = reinterpret_cast<const vfloat4*>(dyv + (size_t)b * TLEN * 2);
    const vfloat4 dA = gd4[(t0m >> 1)];
    const vfloat4 dB = gd4[(t0m >> 1) + 1];

    // ---- uniform params as row/col pairs ----
    const float dts = dtp[0];
    const vfloat2 CdColA = {Cm[0] * dts, Cm[2] * dts};     // (Cd00, Cd10)
    const vfloat2 CdColB = {Cm[1] * dts, Cm[3] * dts};     // (Cd01, Cd11)
    const vfloat2 nCdRow0 = {-Cm[0] * dts, -Cm[1] * dts};  // -(Cd00, Cd01)
    const vfloat2 nCdRow1 = {-Cm[2] * dts, -Cm[3] * dts};  // -(Cd10, Cd11)
    const vfloat2 AdRow0 = {1.f + cA[0] * dts, cA[1] * dts};
    const vfloat2 AdRow1 = {cA[2] * dts, 1.f + cA[3] * dts};
    const float xa = x0[2 * b], xb = x0[2 * b + 1];

    // ---- drain this wave's LDS-DMA (and dy) before reading LDS ----
    asm volatile("s_waitcnt vmcnt(0)" ::: "memory");

    // ---- read own 4 timesteps: swizzled ds_read_b128 ----
    vfloat4 xc[SPT];
#pragma unroll
    for (int s = 0; s < SPT; ++s) {
        const int gw  = 4 * lane + s;
        const int pos = gw ^ ((gw >> 3) & 7);
        xc[s] = s_xc[wv * 256 + pos];
    }
    const float dy0s[SPT] = {dA.x, dA.z, dB.x, dB.z};
    const float dy1s[SPT] = {dA.y, dA.w, dB.y, dB.w};

    // ---- per-step affine rows (Sa,Sb) + offset pair, compose in time order ----
    vfloat2 Sa[SPT], Sb[SPT], ov[SPT];
    vfloat2 mA = {1.f, 0.f}, mB = {0.f, 1.f}, cc = {0.f, 0.f};
#pragma unroll
    for (int s = 0; s < SPT; ++s) {
        const vfloat4 xi = xc[s];
        const vfloat2 sa = AdRow0 + xi.x * nCdRow0 + xi.y * nCdRow1;  // (S00,S01)
        const vfloat2 sb = AdRow1 + xi.z * nCdRow0 + xi.w * nCdRow1;  // (S10,S11)
        const float o0 = xi.x * dy0s[s] + xi.y * dy1s[s];
        const float o1 = xi.z * dy0s[s] + xi.w * dy1s[s];
        Sa[s] = sa; Sb[s] = sb; ov[s] = vfloat2{o0, o1};
        // M = S o M ; c = S c + o
        const vfloat2 nA = sa.x * mA + sa.y * mB;
        const vfloat2 nB = sb.x * mA + sb.y * mB;
        const float nc0 = sa.x * cc.x + sa.y * cc.y + o0;
        const float nc1 = sb.x * cc.x + sb.y * cc.y + o1;
        mA = nA; mB = nB; cc = vfloat2{nc0, nc1};
    }
    if (!valid) { mA = vfloat2{1.f, 0.f}; mB = vfloat2{0.f, 1.f}; cc = vfloat2{0.f, 0.f}; }

    // ---- wave-level inclusive scan via DPP + packed combine ----
#define SCAN_STEP(CTRL, RM)                                          \
    do {                                                             \
        vfloat2 smA, smB, scc;                                       \
        smA.x = dppf<CTRL, RM>(1.f, mA.x);                           \
        smA.y = dppf<CTRL, RM>(0.f, mA.y);                           \
        smB.x = dppf<CTRL, RM>(0.f, mB.x);                           \
        smB.y = dppf<CTRL, RM>(1.f, mB.y);                           \
        scc.x = dppf<CTRL, RM>(0.f, cc.x);                           \
        scc.y = dppf<CTRL, RM>(0.f, cc.y);                           \
        const vfloat2 nA = mA.x * smA + mA.y * smB;                  \
        const vfloat2 nB = mB.x * smA + mB.y * smB;                  \
        const float nc0 = mA.x * scc.x + mA.y * scc.y + cc.x;        \
        const float nc1 = mB.x * scc.x + mB.y * scc.y + cc.y;        \
        mA = nA; mB = nB; cc = vfloat2{nc0, nc1};                    \
    } while (0)

    SCAN_STEP(0x111, 0xf);  // row_shr:1
    SCAN_STEP(0x112, 0xf);  // row_shr:2
    SCAN_STEP(0x114, 0xf);  // row_shr:4
    SCAN_STEP(0x118, 0xf);  // row_shr:8
    SCAN_STEP(0x142, 0xa);  // row_bcast:15 -> rows 1,3
    SCAN_STEP(0x143, 0xc);  // row_bcast:31 -> rows 2,3
#undef SCAN_STEP

    // ---- inter-wave fixup ----
    if (lane == 63) {
        wsum[wv][0] = mA.x; wsum[wv][1] = mA.y;
        wsum[wv][2] = mB.x; wsum[wv][3] = mB.y;
        wsum[wv][4] = cc.x; wsum[wv][5] = cc.y;
    }
    __syncthreads();

    vfloat2 pA = {1.f, 0.f}, pB = {0.f, 1.f}, pc = {0.f, 0.f};
    for (int w = 0; w < wv; ++w) {
        const vfloat2 tA = {wsum[w][0], wsum[w][1]};
        const vfloat2 tB = {wsum[w][2], wsum[w][3]};
        const vfloat2 tc = {wsum[w][4], wsum[w][5]};
        const vfloat2 nA = tA.x * pA + tA.y * pB;   // P = T_w o P
        const vfloat2 nB = tB.x * pA + tB.y * pB;
        const float nc0 = tA.x * pc.x + tA.y * pc.y + tc.x;
        const float nc1 = tB.x * pc.x + tB.y * pc.y + tc.y;
        pA = nA; pB = nB; pc = vfloat2{nc0, nc1};
    }

    // ---- within-wave exclusive = inclusive of lane-1 ----
    vfloat2 eA, eB, ec;
    eA.x = __shfl_up(mA.x, 1); eA.y = __shfl_up(mA.y, 1);
    eB.x = __shfl_up(mB.x, 1); eB.y = __shfl_up(mB.y, 1);
    ec.x = __shfl_up(cc.x, 1); ec.y = __shfl_up(cc.y, 1);
    if (lane == 0) { eA = vfloat2{1.f, 0.f}; eB = vfloat2{0.f, 1.f}; ec = vfloat2{0.f, 0.f}; }

    // E = e o P
    const vfloat2 EA = eA.x * pA + eA.y * pB;
    const vfloat2 EB = eB.x * pA + eB.y * pB;
    const float Ec0 = eA.x * pc.x + eA.y * pc.y + ec.x;
    const float Ec1 = eB.x * pc.x + eB.y * pc.y + ec.y;

    // start state for this chunk: x_{t0-1} = E(x0)
    float xq0 = EA.x * xa + EA.y * xb + Ec0;
    float xq1 = EB.x * xa + EB.y * xb + Ec1;

    // ---- replay chunk, emit outputs (Cd folded; pair = (o0,o1) adjacent) ----
    vfloat2 op[SPT];
#pragma unroll
    for (int s = 0; s < SPT; ++s) {
        op[s] = xq0 * CdColA + xq1 * CdColB;
        const float nx0 = Sa[s].x * xq0 + Sa[s].y * xq1 + ov[s].x;
        const float nx1 = Sb[s].x * xq0 + Sb[s].y * xq1 + ov[s].y;
        xq0 = nx0; xq1 = nx1;
    }

    if (valid) {
        float* ob = out + (size_t)b * TLEN * 2 + (size_t)t0 * 2;
        vfloat4 w0 = {op[0].x, op[0].y, op[1].x, op[1].y};
        vfloat4 w1 = {op[2].x, op[2].y, op[3].x, op[3].y};
        __builtin_nontemporal_store(w0, reinterpret_cast<vfloat4*>(ob));
        __builtin_nontemporal_store(w1, reinterpret_cast<vfloat4*>(ob) + 1);
    }
    if (t0 == TLEN - SPT) {   // owns steps 996..999 -> final state
        vfloat2 xf = {xq0, xq1};
        __builtin_nontemporal_store(
            xf, reinterpret_cast<vfloat2*>(out + (size_t)BATCH * TLEN * 2 + 2 * b));
    }
}

extern "C" void kernel_launch(void* const* d_in, const int* in_sizes, int n_in,
                              void* d_out, int out_size, void* d_ws, size_t ws_size,
                              hipStream_t stream) {
    const float* xicovs = (const float*)d_in[0];
    const float* dyv    = (const float*)d_in[1];
    const float* cA     = (const float*)d_in[2];
    const float* Cm     = (const float*)d_in[3];
    const float* x0     = (const float*)d_in[4];
    const float* dtp    = (const float*)d_in[5];
    float* out = (float*)d_out;

    gd_scan_kernel<<<BATCH, TPB, 0, stream>>>(xicovs, dyv, cA, Cm, x0, dtp, out);
}